// Round 4
// baseline (10153.342 us; speedup 1.0000x reference)
//
#include <hip/hip_runtime.h>

#define NN 1024
#define NOPEN 128
#define NHID 256
#define NSTART 40
#define NCLOSE 3
#define NLAYERS 40
#define KSZ 9
#define GRID_NB 256

static constexpr float H2 = 0.01f;     // h*h, h = 0.1
static constexpr float IN_EPS = 1e-5f; // instance norm eps

using floatx4 = __attribute__((ext_vector_type(4))) float;
using bfrag = __attribute__((ext_vector_type(8))) short; // 8 bf16 = 4 VGPRs

__device__ __forceinline__ ushort f2bf(float f) {
    union { float f; unsigned u; } v; v.f = f;
    unsigned r = v.u + 0x7fffu + ((v.u >> 16) & 1u); // RNE
    return (ushort)(r >> 16);
}

// ---------------- grid barrier: sense-reversing, device scope ----------------
__device__ __forceinline__ void gbar(unsigned* bar) {
    __syncthreads();
    if (threadIdx.x == 0) {
        __threadfence();  // release: flush this XCD's stores to device scope
        unsigned g = __hip_atomic_load(&bar[1], __ATOMIC_RELAXED, __HIP_MEMORY_SCOPE_AGENT);
        unsigned pos = __hip_atomic_fetch_add(&bar[0], 1u, __ATOMIC_ACQ_REL, __HIP_MEMORY_SCOPE_AGENT);
        if (pos == GRID_NB - 1u) {
            __hip_atomic_store(&bar[0], 0u, __ATOMIC_RELAXED, __HIP_MEMORY_SCOPE_AGENT);
            __threadfence();
            __hip_atomic_fetch_add(&bar[1], 1u, __ATOMIC_RELEASE, __HIP_MEMORY_SCOPE_AGENT);
        } else {
            while (__hip_atomic_load(&bar[1], __ATOMIC_RELAXED, __HIP_MEMORY_SCOPE_AGENT) == g)
                __builtin_amdgcn_s_sleep(2);
        }
        __threadfence();  // acquire: invalidate local caches
    }
    __syncthreads();
}

// ---------------- opening (separate kernel): Zc, Zold, Zct(layer0), pads, bar ----------------
__global__ void k_open(const float* __restrict__ Kopen, const float* __restrict__ Z,
                       float* __restrict__ Zc, float* __restrict__ Zold,
                       const float* __restrict__ Bias0, ushort* __restrict__ Zct,
                       ushort* __restrict__ At0, ushort* __restrict__ At1,
                       unsigned* __restrict__ bar) {
    int n = blockIdx.x * 256 + threadIdx.x;
    int o = blockIdx.y;
    float acc = 0.f;
#pragma unroll
    for (int s = 0; s < NSTART; ++s)
        acc = fmaf(Kopen[o * NSTART + s], Z[s * NN + n], acc);
    Zc[o * NN + n] = acc;
    Zold[o * NN + n] = acc;
#pragma unroll
    for (int z = 0; z < 2; ++z)
        Zct[z * (1032 * 128) + (n + 4) * 128 + o] = f2bf(acc + Bias0[z * NOPEN + o]);
    if (blockIdx.x == 0 && blockIdx.y == 0) {
        int tid = threadIdx.x;
        if (tid == 0) { bar[0] = 0u; bar[1] = 0u; }
        // Zct pads: rows 0..3 and 1028..1031, both z
        for (int idx = tid; idx < 1024; idx += 256) {
            int z = idx >> 9, rr = idx & 511;
            ushort* Zz = Zct + z * (1032 * 128);
            Zz[rr] = 0; Zz[1028 * 128 + rr] = 0;
        }
        // At pads: rows 0..3 and 1028..1031, both arrays
        for (int idx = tid; idx < 2048; idx += 256) {
            int a = idx >> 10, rr = idx & 1023;
            ushort* A = a ? At1 : At0;
            A[rr] = 0; A[1028 * 256 + rr] = 0;
        }
    }
}

// ---------------- phase pieces (device functions) ----------------

// weight transpose prep: lb<72 -> Wt[t][co][ci]; else WtT[t][ci][co]
__device__ __forceinline__ void prepw_piece(const float* __restrict__ W, ushort* __restrict__ Wt,
                                            ushort* __restrict__ WtT, int lb, int lsrc, int slot, int tid) {
    if (lb < 72) {
        int q = lb; int coq = q & 3; q >>= 2; int t = q % 9, z = q / 9;
        const float* Wz = W + (size_t)(lsrc * 2 + z) * (NHID * NOPEN * KSZ);
        ushort* Wo = Wt + ((size_t)(slot * 2 + z) * 9 + t) * (NHID * NOPEN);
#pragma unroll
        for (int r = 0; r < 32; ++r) {
            int idx = r * 256 + tid;
            int co = coq * 64 + (idx >> 7), ci = idx & 127;
            Wo[co * NOPEN + ci] = f2bf(Wz[co * (NOPEN * KSZ) + ci * KSZ + t]);
        }
    } else {
        int q = lb - 72; int ciq = q & 3; q >>= 2; int t = q % 9, z = q / 9;
        const float* Wz = W + (size_t)(lsrc * 2 + z) * (NHID * NOPEN * KSZ);
        ushort* Wo = WtT + ((size_t)(slot * 2 + z) * 9 + t) * (NOPEN * NHID);
#pragma unroll
        for (int r = 0; r < 32; ++r) {
            int idx = r * 256 + tid;
            int ci = ciq * 32 + (idx >> 8), co = idx & 255;
            Wo[ci * NHID + co] = f2bf(Wz[co * (NOPEN * KSZ) + ci * KSZ + t]);
        }
    }
}

// sq[i] = sum_c Zc[c,i]^2 ; zero sigma
__device__ __forceinline__ void sq_piece(int v, const float* __restrict__ Zc,
                                         float* __restrict__ sqv, float* __restrict__ sig, int tid) {
    int i = v * 256 + tid;
    float a = 0.f;
    for (int c = 0; c < NOPEN; ++c) { float x = Zc[c * NN + i]; a = fmaf(x, x, a); }
    sqv[i] = a;
    if (v == 0 && tid == 0) sig[0] = 0.f;
}

// D2 tile + sum(D2) accumulation
__device__ __forceinline__ void d2_piece(int v, const float* __restrict__ Zc, const float* __restrict__ sqv,
                                         float* __restrict__ D2, float* __restrict__ sig,
                                         ushort* sm, int tid) {
    float* Zi = (float*)sm;          // 32*36
    float* Zj = Zi + 1152;           // 32*68
    float* red = Zi + 3328;          // 4
    const int tx = tid & 15, ty = tid >> 4;
    const int j0 = (v & 15) * 64, i0 = (v >> 4) * 32;
    float acc[2][4] = {};
    for (int c0 = 0; c0 < NOPEN; c0 += 32) {
        for (int idx = tid; idx < 32 * 32; idx += 256) {
            int c = idx >> 5, ii = idx & 31;
            Zi[c * 36 + ii] = Zc[(c0 + c) * NN + i0 + ii];
        }
        for (int idx = tid; idx < 32 * 64; idx += 256) {
            int c = idx >> 6, jj = idx & 63;
            Zj[c * 68 + jj] = Zc[(c0 + c) * NN + j0 + jj];
        }
        __syncthreads();
#pragma unroll 8
        for (int c = 0; c < 32; ++c) {
            float2 zi = *(const float2*)&Zi[c * 36 + ty * 2];
            float4 zj = *(const float4*)&Zj[c * 68 + tx * 4];
            acc[0][0] = fmaf(zi.x, zj.x, acc[0][0]);
            acc[0][1] = fmaf(zi.x, zj.y, acc[0][1]);
            acc[0][2] = fmaf(zi.x, zj.z, acc[0][2]);
            acc[0][3] = fmaf(zi.x, zj.w, acc[0][3]);
            acc[1][0] = fmaf(zi.y, zj.x, acc[1][0]);
            acc[1][1] = fmaf(zi.y, zj.y, acc[1][1]);
            acc[1][2] = fmaf(zi.y, zj.z, acc[1][2]);
            acc[1][3] = fmaf(zi.y, zj.w, acc[1][3]);
        }
        __syncthreads();
    }
    float part = 0.f;
#pragma unroll
    for (int m = 0; m < 2; ++m) {
        int i = i0 + ty * 2 + m;
        float sqi = sqv[i];
        float4 d;
        d.x = fmaxf(sqi + sqv[j0 + tx * 4 + 0] - 2.f * acc[m][0], 0.f);
        d.y = fmaxf(sqi + sqv[j0 + tx * 4 + 1] - 2.f * acc[m][1], 0.f);
        d.z = fmaxf(sqi + sqv[j0 + tx * 4 + 2] - 2.f * acc[m][2], 0.f);
        d.w = fmaxf(sqi + sqv[j0 + tx * 4 + 3] - 2.f * acc[m][3], 0.f);
        *(float4*)&D2[(size_t)i * NN + j0 + tx * 4] = d;
        part += (d.x + d.y) + (d.z + d.w);
    }
#pragma unroll
    for (int off = 32; off > 0; off >>= 1) part += __shfl_down(part, off);
    if ((tid & 63) == 0) red[tid >> 6] = part;
    __syncthreads();
    if (tid == 0) atomicAdd(sig, red[0] + red[1] + red[2] + red[3]);
    __syncthreads();
}

__device__ __forceinline__ void deg_piece(int v, const float* __restrict__ D2, const float* __restrict__ sig,
                                          float* __restrict__ Dh, ushort* sm, int tid) {
    float* red = (float*)sm;
    float inv = 1.f / (sig[0] * (1.f / 1048576.f) + 1e-12f);
    float4 x = *(const float4*)&D2[(size_t)v * NN + tid * 4];
    float s = __expf(-x.x * inv) + __expf(-x.y * inv) + __expf(-x.z * inv) + __expf(-x.w * inv);
#pragma unroll
    for (int off = 32; off > 0; off >>= 1) s += __shfl_down(s, off);
    if ((tid & 63) == 0) red[tid >> 6] = s;
    __syncthreads();
    if (tid == 0) Dh[v] = rsqrtf(red[0] + red[1] + red[2] + red[3]);
    __syncthreads();
}

__device__ __forceinline__ void kl_piece(int v, const float* __restrict__ D2, const float* __restrict__ sig,
                                         const float* __restrict__ Dh, ushort* __restrict__ Lb, int tid) {
    int i = v, j = tid * 4;
    float inv = 1.f / (sig[0] * (1.f / 1048576.f) + 1e-12f);
    float dhi = Dh[i];
    float4 x = *(const float4*)&D2[(size_t)i * NN + j];
    float4 dj = *(const float4*)&Dh[j];
    float4 o;
    o.x = -dhi * dj.x * __expf(-x.x * inv);
    o.y = -dhi * dj.y * __expf(-x.y * inv);
    o.z = -dhi * dj.z * __expf(-x.z * inv);
    o.w = -dhi * dj.w * __expf(-x.w * inv);
    if (i == j + 0) o.x += 1.f;
    if (i == j + 1) o.y += 1.f;
    if (i == j + 2) o.z += 1.f;
    if (i == j + 3) o.w += 1.f;
    ushort4 ob; ob.x = f2bf(o.x); ob.y = f2bf(o.y); ob.z = f2bf(o.z); ob.w = f2bf(o.w);
    *(ushort4*)&Lb[(size_t)i * NN + j] = ob;
}

// MFMA conv1d: vb = p-tile(16) x co-tile(8) x z(2)
__device__ __forceinline__ void conv_phase(int vb, const ushort* __restrict__ Zct,
        const ushort* __restrict__ Wt_l, float* __restrict__ C0, ushort* __restrict__ C1b,
        ushort* sm, int tid) {
    const int pt = vb & 15, ct = (vb >> 4) & 7, z = vb >> 7;
    const int p0 = pt * 64, co0 = ct * 32;
    ushort* Xs = sm;             // 72*136
    ushort* Wl = sm + 9792;      // 9*32*136
    const ushort* Zz = Zct + z * (1032 * 128);
    const ushort* Wz = Wt_l + (size_t)z * 9 * NHID * NOPEN;
    for (int idx = tid; idx < 1152; idx += 256) {
        int row = idx >> 4, ch = (idx & 15) * 8;
        *(bfrag*)&Xs[row * 136 + ch] = *(const bfrag*)&Zz[(p0 + row) * 128 + ch];
    }
    for (int idx = tid; idx < 4608; idx += 256) {
        int t = idx >> 9, rem = idx & 511;
        int c = rem >> 4, ch = (rem & 15) * 8;
        *(bfrag*)&Wl[(t * 32 + c) * 136 + ch] = *(const bfrag*)&Wz[(t * NHID + co0 + c) * 128 + ch];
    }
    __syncthreads();
    const int l = tid & 63, wv = tid >> 6;
    const int wm = wv >> 1, wn = wv & 1;
    const int lm = l & 15, lq = l >> 4;
    floatx4 acc[2] = {};
    for (int t = 0; t < 9; ++t) {
        const int wbase = (t * 32 + wm * 16 + lm) * 136 + lq * 8;
        const int xbase = (wn * 32 + lm + t) * 136 + lq * 8;
#pragma unroll
        for (int kc = 0; kc < 4; ++kc) {
            bfrag a = *(const bfrag*)&Wl[wbase + kc * 32];
            bfrag b0 = *(const bfrag*)&Xs[xbase + kc * 32];
            acc[0] = __builtin_amdgcn_mfma_f32_16x16x32_bf16(a, b0, acc[0], 0, 0, 0);
            bfrag b1 = *(const bfrag*)&Xs[xbase + 16 * 136 + kc * 32];
            acc[1] = __builtin_amdgcn_mfma_f32_16x16x32_bf16(a, b1, acc[1], 0, 0, 0);
        }
    }
    __syncthreads();
    const int cog = co0 + wm * 16 + lq * 4;
    const int pg = p0 + wn * 32 + lm;
#pragma unroll
    for (int j = 0; j < 2; ++j)
#pragma unroll
        for (int r = 0; r < 4; ++r) {
            if (z == 0) C0[(cog + r) * NN + pg + j * 16] = acc[j][r];
            else        C1b[(cog + r) * NN + pg + j * 16] = f2bf(acc[j][r]);
        }
}

// MFMA GEMM vs symmetric L: Out[m0..+64, n0..+64] over K range [k0, k0+512)
__device__ __forceinline__ void xlfull_piece(const ushort* __restrict__ X, const ushort* __restrict__ Lb,
        float* __restrict__ Out, int m0, int n0, int k0, ushort* sm, int tid) {
    ushort* As = sm;           // 64*136
    ushort* Bs = sm + 8704;    // 64*136
    const int lane = tid & 63, wave = tid >> 6;
    const int wm = wave >> 1, wn = wave & 1;
    const int lm = lane & 15, lq = lane >> 4;
    floatx4 acc[2][2] = {};
    for (int kc = k0; kc < k0 + 512; kc += 128) {
#pragma unroll
        for (int r = 0; r < 4; ++r) {
            int q = r * 256 + tid;
            int row = q >> 4, ch = (q & 15) * 8;
            *(bfrag*)&As[row * 136 + ch] = *(const bfrag*)&X[(m0 + row) * NN + kc + ch];
            *(bfrag*)&Bs[row * 136 + ch] = *(const bfrag*)&Lb[(n0 + row) * NN + kc + ch];
        }
        __syncthreads();
#pragma unroll
        for (int ks = 0; ks < 4; ++ks) {
            bfrag a[2], b[2];
#pragma unroll
            for (int i = 0; i < 2; ++i)
                a[i] = *(const bfrag*)&As[(wm * 32 + i * 16 + lm) * 136 + ks * 32 + lq * 8];
#pragma unroll
            for (int j = 0; j < 2; ++j)
                b[j] = *(const bfrag*)&Bs[(wn * 32 + j * 16 + lm) * 136 + ks * 32 + lq * 8];
#pragma unroll
            for (int i = 0; i < 2; ++i)
#pragma unroll
                for (int j = 0; j < 2; ++j)
                    acc[i][j] = __builtin_amdgcn_mfma_f32_16x16x32_bf16(a[i], b[j], acc[i][j], 0, 0, 0);
        }
        __syncthreads();
    }
    const int mg0 = m0 + wm * 32 + lq * 4;
    const int ng0 = n0 + wn * 32 + lm;
#pragma unroll
    for (int i = 0; i < 2; ++i)
#pragma unroll
        for (int j = 0; j < 2; ++j)
#pragma unroll
            for (int r = 0; r < 4; ++r)
                Out[(size_t)(mg0 + i * 16 + r) * NN + ng0 + j * 16] = acc[i][j][r];
}

// instance-norm stats (redundant per block) + relu + bf16 + transpose -> out[pos+4][co]
// in2 != null: value = in + in2 (split-K partials)
__device__ __forceinline__ void normT_piece(int vb, const float* __restrict__ in,
        const float* __restrict__ in2, ushort* __restrict__ out, ushort* sm, int tid) {
    const int pt = vb & 15, ct = vb >> 4;
    const int p0 = pt * 64, co0 = ct * 64;
    float* ps = (float*)sm;          // 256
    float* pqv = ps + 256;           // 256
    float* mu = ps + 512;            // 64
    float* rsx = ps + 576;           // 64
    ushort* Ls = sm + 1280;          // 64*72
    {
        const int ch = tid >> 2, q = tid & 3;
        const float* row = in + (size_t)(co0 + ch) * NN;
        const float* row2 = in2 ? in2 + (size_t)(co0 + ch) * NN : row;
        float s = 0.f, qq = 0.f;
        for (int j = 0; j < 64; ++j) {
            int f = (j * 4 + q) * 4;
            float4 v = *(const float4*)&row[f];
            if (in2) {
                float4 w = *(const float4*)&row2[f];
                v.x += w.x; v.y += w.y; v.z += w.z; v.w += w.w;
            }
            s += (v.x + v.y) + (v.z + v.w);
            qq += (v.x * v.x + v.y * v.y) + (v.z * v.z + v.w * v.w);
        }
        ps[ch * 4 + q] = s; pqv[ch * 4 + q] = qq;
    }
    __syncthreads();
    if (tid < 64) {
        float S = ps[tid * 4] + ps[tid * 4 + 1] + ps[tid * 4 + 2] + ps[tid * 4 + 3];
        float Q = pqv[tid * 4] + pqv[tid * 4 + 1] + pqv[tid * 4 + 2] + pqv[tid * 4 + 3];
        float mean = S * (1.f / NN);
        float var = Q * (1.f / NN) - mean * mean;
        mu[tid] = mean;
        rsx[tid] = rsqrtf(var + IN_EPS);
    }
    __syncthreads();
#pragma unroll
    for (int r = 0; r < 4; ++r) {
        int idx = r * 256 + tid;
        int col = idx >> 4, pq2 = idx & 15;
        const float* rp = in + (size_t)(co0 + col) * NN + p0 + pq2 * 4;
        float4 v = *(const float4*)rp;
        if (in2) {
            float4 w = *(const float4*)(in2 + (size_t)(co0 + col) * NN + p0 + pq2 * 4);
            v.x += w.x; v.y += w.y; v.z += w.z; v.w += w.w;
        }
        float m = mu[col], sc = rsx[col];
        Ls[(pq2 * 4 + 0) * 72 + col] = f2bf(fmaxf((v.x - m) * sc, 0.f));
        Ls[(pq2 * 4 + 1) * 72 + col] = f2bf(fmaxf((v.y - m) * sc, 0.f));
        Ls[(pq2 * 4 + 2) * 72 + col] = f2bf(fmaxf((v.z - m) * sc, 0.f));
        Ls[(pq2 * 4 + 3) * 72 + col] = f2bf(fmaxf((v.w - m) * sc, 0.f));
    }
    __syncthreads();
#pragma unroll
    for (int r = 0; r < 2; ++r) {
        int idx = r * 256 + tid;
        int row = idx >> 3, ch8 = (idx & 7) * 8;
        *(bfrag*)&out[(size_t)(p0 + row + 4) * 256 + co0 + ch8] = *(const bfrag*)&Ls[row * 72 + ch8];
    }
    __syncthreads();
}

// MFMA convT: vb = p-tile(16) x ci-tile(8); z selects input/weights/output
__device__ __forceinline__ void convT_phase(int vb, int z, const ushort* __restrict__ At0,
        const ushort* __restrict__ At1, const ushort* __restrict__ WtT_l,
        float* __restrict__ Tacc, ushort* __restrict__ T1b, ushort* sm, int tid) {
    const int pt = vb & 15, cit = vb >> 4;
    const int p0 = pt * 64, ci0 = cit * 16;
    ushort* Al = sm;             // 72*264
    ushort* Wl = sm + 19008;     // 9*16*264
    const ushort* A = z ? At1 : At0;
    const ushort* Wz = WtT_l + (size_t)z * 9 * NOPEN * NHID;
    for (int idx = tid; idx < 2304; idx += 256) {
        int row = idx >> 5, ch = (idx & 31) * 8;
        *(bfrag*)&Al[row * 264 + ch] = *(const bfrag*)&A[(p0 + row) * 256 + ch];
    }
    for (int idx = tid; idx < 4608; idx += 256) {
        int t = idx >> 9, rem = idx & 511;
        int c = rem >> 5, ch = (rem & 31) * 8;
        *(bfrag*)&Wl[(t * 16 + c) * 264 + ch] = *(const bfrag*)&Wz[(t * NOPEN + ci0 + c) * 256 + ch];
    }
    __syncthreads();
    const int l = tid & 63, wv = tid >> 6;
    const int lm = l & 15, lq = l >> 4;
    floatx4 acc0 = {}, acc1 = {};
    for (int t = 0; t < 9; ++t) {
        const int abase = (wv * 16 + lm + 8 - t) * 264 + lq * 8;
        const int wbase = (t * 16 + lm) * 264 + lq * 8;
#pragma unroll
        for (int kc = 0; kc < 8; kc += 2) {
            bfrag a0 = *(const bfrag*)&Wl[wbase + kc * 32];
            bfrag b0 = *(const bfrag*)&Al[abase + kc * 32];
            acc0 = __builtin_amdgcn_mfma_f32_16x16x32_bf16(a0, b0, acc0, 0, 0, 0);
            bfrag a1 = *(const bfrag*)&Wl[wbase + kc * 32 + 32];
            bfrag b1 = *(const bfrag*)&Al[abase + kc * 32 + 32];
            acc1 = __builtin_amdgcn_mfma_f32_16x16x32_bf16(a1, b1, acc1, 0, 0, 0);
        }
    }
    __syncthreads();
    floatx4 acc = acc0 + acc1;
    const int cig = ci0 + lq * 4;
    const int pg = p0 + wv * 16 + lm;
#pragma unroll
    for (int r = 0; r < 4; ++r) {
        if (z == 0) Tacc[(cig + r) * NN + pg] = acc[r];
        else        T1b[(cig + r) * NN + pg] = f2bf(acc[r]);
    }
}

// leapfrog + build next layer's Zct
__device__ __forceinline__ void leap_piece(int v, const float* __restrict__ A2,
        const float* __restrict__ Tacc, const float* __restrict__ Zc, float* __restrict__ Zo,
        const float* __restrict__ BiasN, ushort* __restrict__ Zct, int tid) {
    int off = (v * 256 + tid) * 4;
    float4 a = *(const float4*)&Tacc[off];
    float4 q0 = *(const float4*)&A2[off];
    float4 q1 = *(const float4*)&A2[NOPEN * NN + off];
    a.x += q0.x + q1.x; a.y += q0.y + q1.y; a.z += q0.z + q1.z; a.w += q0.w + q1.w;
    float4 zc = *(const float4*)&Zc[off];
    float4 zo = *(const float4*)&Zo[off];
    float4 zn;
    zn.x = 2.f * zc.x - zo.x - H2 * a.x;
    zn.y = 2.f * zc.y - zo.y - H2 * a.y;
    zn.z = 2.f * zc.z - zo.z - H2 * a.z;
    zn.w = 2.f * zc.w - zo.w - H2 * a.w;
    *(float4*)&Zo[off] = zn;
    int ci = off >> 10, n = off & 1023;
#pragma unroll
    for (int z = 0; z < 2; ++z) {
        float bz = BiasN[z * NOPEN + ci];
        ushort* Zz = Zct + z * (1032 * 128);
        Zz[(n + 4) * 128 + ci] = f2bf(zn.x + bz);
        Zz[(n + 5) * 128 + ci] = f2bf(zn.y + bz);
        Zz[(n + 6) * 128 + ci] = f2bf(zn.z + bz);
        Zz[(n + 7) * 128 + ci] = f2bf(zn.w + bz);
    }
}

__device__ __forceinline__ void close_piece(int v, const float* __restrict__ Kclose,
        const float* __restrict__ Zcf, const float* __restrict__ Zof,
        float* __restrict__ out, int tid) {
    int nb = v & 3, rest = v >> 2;
    int o = rest % 3, zsel = rest / 3;
    int n = nb * 256 + tid;
    const float* Zb = zsel ? Zof : Zcf;
    float a = 0.f;
#pragma unroll
    for (int c = 0; c < NOPEN; ++c) a = fmaf(Kclose[o * NOPEN + c], Zb[c * NN + n], a);
    out[zsel * (NCLOSE * NN) + o * NN + n] = a;
}

// ---------------- the mega kernel: whole layer loop, 1 block/CU ----------------
__global__ __launch_bounds__(256, 1) void k_mega(
        float* __restrict__ Zb0, float* __restrict__ Zb1, float* __restrict__ D2,
        float* __restrict__ C0, float* __restrict__ A1, float* __restrict__ A2,
        float* __restrict__ Tacc, float* __restrict__ sqv, float* __restrict__ Dh,
        float* __restrict__ sig, unsigned* __restrict__ bar, ushort* __restrict__ Lb,
        ushort* __restrict__ C1b, ushort* __restrict__ T1b, ushort* __restrict__ Zct,
        ushort* __restrict__ At0, ushort* __restrict__ At1, ushort* __restrict__ Wt,
        ushort* __restrict__ WtT, const float* __restrict__ W, const float* __restrict__ Bias,
        const float* __restrict__ Kclose, float* __restrict__ out, int nlw) {
    __shared__ ushort sm[57024]; // 114048 B, forces 1 block/CU
    const int bid = blockIdx.x, tid = threadIdx.x;
    const bool hoist = (nlw == NLAYERS);

    // pre-loop: weight transposes (all layers if hoisted, else layer 0)
    for (int v = bid; v < 144 * nlw; v += GRID_NB)
        prepw_piece(W, Wt, WtT, v % 144, hoist ? v / 144 : 0, hoist ? v / 144 : 0, tid);
    gbar(bar);

    bool flip = false;
    for (int l = 0; l < NLAYERS; ++l) {
        float* Zc = flip ? Zb1 : Zb0;
        float* Zo = flip ? Zb0 : Zb1;
        const int slot = hoist ? l : 0;
        const ushort* Wt_l = Wt + (size_t)slot * 2 * 9 * NHID * NOPEN;
        const ushort* WtT_l = WtT + (size_t)slot * 2 * 9 * NOPEN * NHID;
        const bool lap = (l % 10) == 0;

        // S0: conv (all 256) + sq on Laplacian layers
        conv_phase(bid, Zct, Wt_l, C0, C1b, sm, tid);
        if (lap && bid < 4) sq_piece(bid, Zc, sqv, sig, tid);
        gbar(bar);
        if (lap) {
            for (int v = bid; v < 512; v += GRID_NB) d2_piece(v, Zc, sqv, D2, sig, sm, tid);
            gbar(bar);
            for (int v = bid; v < 1024; v += GRID_NB) deg_piece(v, D2, sig, Dh, sm, tid);
            gbar(bar);
            for (int v = bid; v < 1024; v += GRID_NB) kl_piece(v, D2, sig, Dh, Lb, tid);
            gbar(bar);
        }
        // S1: xl1 split-2 (128) + normT0 (64)
        if (bid < 128) {
            int nt = bid & 15, mt = (bid >> 4) & 3, ksp = bid >> 6;
            xlfull_piece(C1b, Lb, A1 + (size_t)ksp * NHID * NN, mt * 64, nt * 64, ksp * 512, sm, tid);
        } else if (bid < 192) {
            normT_piece(bid - 128, C0, nullptr, At0, sm, tid);
        }
        gbar(bar);
        // S2: normT1 (64, sums 2 xl1 partials) + convT z=0 (128)
        if (bid < 64) {
            normT_piece(bid, A1, A1 + (size_t)NHID * NN, At1, sm, tid);
        } else if (bid < 192) {
            convT_phase(bid - 64, 0, At0, At1, WtT_l, Tacc, T1b, sm, tid);
        }
        gbar(bar);
        // S3: convT z=1 (128)
        if (bid < 128) convT_phase(bid, 1, At0, At1, WtT_l, Tacc, T1b, sm, tid);
        gbar(bar);
        // S4: xl2 split-2 (64)
        if (bid < 64) {
            int nt = bid & 15, mt = (bid >> 4) & 1, ksp = bid >> 5;
            xlfull_piece(T1b, Lb, A2 + (size_t)ksp * NOPEN * NN, mt * 64, nt * 64, ksp * 512, sm, tid);
        }
        gbar(bar);
        // S5: leap (128) + (fallback) prep next layer's weights
        {
            const float* BiasN = Bias + (size_t)((l + 1 < NLAYERS) ? l + 1 : l) * 2 * NOPEN;
            int nv = 128 + ((!hoist && l + 1 < NLAYERS) ? 144 : 0);
            for (int v = bid; v < nv; v += GRID_NB) {
                if (v < 128) leap_piece(v, A2, Tacc, Zc, Zo, BiasN, Zct, tid);
                else prepw_piece(W, Wt, WtT, v - 128, l + 1, 0, tid);
            }
        }
        gbar(bar);
        flip = !flip;
    }
    // close
    const float* Zcf = flip ? Zb1 : Zb0;
    const float* Zof = flip ? Zb0 : Zb1;
    if (bid < 24) close_piece(bid, Kclose, Zcf, Zof, out, tid);
}

extern "C" void kernel_launch(void* const* d_in, const int* in_sizes, int n_in,
                              void* d_out, int out_size, void* d_ws, size_t ws_size,
                              hipStream_t stream) {
    const float* Z      = (const float*)d_in[0];
    const float* Kopen  = (const float*)d_in[1];
    const float* Kclose = (const float*)d_in[2];
    const float* W      = (const float*)d_in[3];
    const float* Bias   = (const float*)d_in[4];
    float* out = (float*)d_out;
    float* ws  = (float*)d_ws;

    // workspace layout (float units)
    float* Zb0  = ws + 0;         // 131072
    float* Zb1  = ws + 131072;    // 131072
    float* D2   = ws + 262144;    // 1048576
    float* C0   = ws + 1310720;   // 262144
    float* A1   = ws + 1572864;   // 524288 (2 splits)
    float* A2   = ws + 2097152;   // 262144 (2 splits)
    float* Tacc = ws + 2359296;   // 131072
    float* sqv  = ws + 2490368;   // 1024
    float* Dh   = ws + 2491392;   // 1024
    float* sig  = ws + 2492416;   // 1024
    unsigned* bar = (unsigned*)(ws + 2493440); // 1024
    ushort* Lb  = (ushort*)(ws + 2494464); // 1024*1024 us
    ushort* C1b = (ushort*)(ws + 3018752); // 256*1024 us
    ushort* T1b = (ushort*)(ws + 3149824); // 128*1024 us
    ushort* Zct = (ushort*)(ws + 3215360); // 2*1032*128 us
    ushort* At0 = (ushort*)(ws + 3347456); // 1032*256 us
    ushort* At1 = (ushort*)(ws + 3479552); // 1032*256 us
    ushort* Wt  = (ushort*)(ws + 3611648); // nlw*2*9*256*128 us
    // hoisted layout needs (3611648 + 40*589824) floats = 108,818,432 bytes
    const size_t NEED_HOIST = 108818432UL;
    int nlw = (ws_size >= NEED_HOIST) ? NLAYERS : 1;
    ushort* WtT = Wt + (size_t)nlw * 2 * 9 * NHID * NOPEN;

    k_open<<<dim3(4, NOPEN), 256, 0, stream>>>(Kopen, Z, Zb0, Zb1, Bias, Zct, At0, At1, bar);
    k_mega<<<dim3(GRID_NB), 256, 0, stream>>>(Zb0, Zb1, D2, C0, A1, A2, Tacc, sqv, Dh, sig,
                                              bar, Lb, C1b, T1b, Zct, At0, At1, Wt, WtT,
                                              W, Bias, Kclose, out, nlw);
}

// Round 5
// 2685.048 us; speedup vs baseline: 3.7814x; 3.7814x over previous
//
#include <hip/hip_runtime.h>

#define NN 1024
#define NOPEN 128
#define NHID 256
#define NSTART 40
#define NCLOSE 3
#define NLAYERS 40
#define KSZ 9

static constexpr float H2 = 0.01f;     // h*h, h = 0.1
static constexpr float IN_EPS = 1e-5f; // instance norm eps

using floatx4 = __attribute__((ext_vector_type(4))) float;
using bfrag = __attribute__((ext_vector_type(8))) short; // 8 bf16 = 4 VGPRs

__device__ __forceinline__ ushort f2bf(float f) {
    union { float f; unsigned u; } v; v.f = f;
    unsigned r = v.u + 0x7fffu + ((v.u >> 16) & 1u); // RNE
    return (ushort)(r >> 16);
}

// weight transpose prep: lb<72 -> Wt[z][t][co][ci]; else WtT[z][t][ci][co]  (slot 0)
__device__ __forceinline__ void prepw_piece(const float* __restrict__ W, ushort* __restrict__ Wt,
                                            ushort* __restrict__ WtT, int lb, int lsrc, int tid) {
    if (lb < 72) {
        int q = lb; int coq = q & 3; q >>= 2; int t = q % 9, z = q / 9;
        const float* Wz = W + (size_t)(lsrc * 2 + z) * (NHID * NOPEN * KSZ);
        ushort* Wo = Wt + ((size_t)z * 9 + t) * (NHID * NOPEN);
#pragma unroll
        for (int r = 0; r < 32; ++r) {
            int idx = r * 256 + tid;
            int co = coq * 64 + (idx >> 7), ci = idx & 127;
            Wo[co * NOPEN + ci] = f2bf(Wz[co * (NOPEN * KSZ) + ci * KSZ + t]);
        }
    } else {
        int q = lb - 72; int ciq = q & 3; q >>= 2; int t = q % 9, z = q / 9;
        const float* Wz = W + (size_t)(lsrc * 2 + z) * (NHID * NOPEN * KSZ);
        ushort* Wo = WtT + ((size_t)z * 9 + t) * (NOPEN * NHID);
#pragma unroll
        for (int r = 0; r < 32; ++r) {
            int idx = r * 256 + tid;
            int ci = ciq * 32 + (idx >> 8), co = idx & 255;
            Wo[ci * NHID + co] = f2bf(Wz[co * (NOPEN * KSZ) + ci * KSZ + t]);
        }
    }
}

// ---------------- opening: Zc/Zold/Zct(layer0) + weight prep(layer0) + pads + sig=0 ----------------
__global__ __launch_bounds__(256) void k_open(const float* __restrict__ Kopen, const float* __restrict__ Z,
                       float* __restrict__ Zc, float* __restrict__ Zold,
                       const float* __restrict__ Bias0, ushort* __restrict__ Zct,
                       ushort* __restrict__ At0, ushort* __restrict__ At1,
                       const float* __restrict__ W, ushort* __restrict__ Wt,
                       ushort* __restrict__ WtT, float* __restrict__ sig) {
    const int v = blockIdx.x, tid = threadIdx.x;
    if (v < 512) {
        int o = v >> 2, n = (v & 3) * 256 + tid;
        float acc = 0.f;
#pragma unroll
        for (int s = 0; s < NSTART; ++s)
            acc = fmaf(Kopen[o * NSTART + s], Z[s * NN + n], acc);
        Zc[o * NN + n] = acc;
        Zold[o * NN + n] = acc;
#pragma unroll
        for (int z = 0; z < 2; ++z)
            Zct[z * (1032 * 128) + (n + 4) * 128 + o] = f2bf(acc + Bias0[z * NOPEN + o]);
    } else if (v < 656) {
        prepw_piece(W, Wt, WtT, v - 512, 0, tid);
    } else {
        if (tid == 0) sig[0] = 0.f;
        for (int idx = tid; idx < 1024; idx += 256) {
            int z = idx >> 9, rr = idx & 511;
            ushort* Zz = Zct + z * (1032 * 128);
            Zz[rr] = 0; Zz[1028 * 128 + rr] = 0;
        }
        for (int idx = tid; idx < 2048; idx += 256) {
            int a = idx >> 10, rr = idx & 1023;
            ushort* A = a ? At1 : At0;
            A[rr] = 0; A[1028 * 256 + rr] = 0;
        }
    }
}

// ---------------- D2 = max(sq_i + sq_j - 2 Z^T Z, 0); sq computed in-block; sum(D2) -> sig ----------------
// grid (16 j-tiles, 32 i-tiles); sig must be zeroed by a previous dispatch.
__global__ __launch_bounds__(256) void k_d2(const float* __restrict__ Zc,
                                            float* __restrict__ D2, float* __restrict__ sig) {
    __shared__ __align__(16) float Zi[32 * 36];
    __shared__ __align__(16) float Zj[32 * 68];
    __shared__ float sqi[32], sqj[64];
    __shared__ float red[4];
    const int tid = threadIdx.x;
    const int tx = tid & 15, ty = tid >> 4;
    const int j0 = blockIdx.x * 64, i0 = blockIdx.y * 32;
    if (tid < 32) sqi[tid] = 0.f;
    else if (tid < 96) sqj[tid - 32] = 0.f;
    float acc[2][4] = {};
    for (int c0 = 0; c0 < NOPEN; c0 += 32) {
        for (int idx = tid; idx < 32 * 32; idx += 256) {
            int c = idx >> 5, ii = idx & 31;
            Zi[c * 36 + ii] = Zc[(c0 + c) * NN + i0 + ii];
        }
        for (int idx = tid; idx < 32 * 64; idx += 256) {
            int c = idx >> 6, jj = idx & 63;
            Zj[c * 68 + jj] = Zc[(c0 + c) * NN + j0 + jj];
        }
        __syncthreads();
        if (tid < 32) {
            float s = 0.f;
            for (int c = 0; c < 32; ++c) { float x = Zi[c * 36 + tid]; s = fmaf(x, x, s); }
            sqi[tid] += s;
        } else if (tid < 96) {
            int jj = tid - 32;
            float s = 0.f;
            for (int c = 0; c < 32; ++c) { float x = Zj[c * 68 + jj]; s = fmaf(x, x, s); }
            sqj[jj] += s;
        }
#pragma unroll 8
        for (int c = 0; c < 32; ++c) {
            float2 zi = *(const float2*)&Zi[c * 36 + ty * 2];
            float4 zj = *(const float4*)&Zj[c * 68 + tx * 4];
            acc[0][0] = fmaf(zi.x, zj.x, acc[0][0]);
            acc[0][1] = fmaf(zi.x, zj.y, acc[0][1]);
            acc[0][2] = fmaf(zi.x, zj.z, acc[0][2]);
            acc[0][3] = fmaf(zi.x, zj.w, acc[0][3]);
            acc[1][0] = fmaf(zi.y, zj.x, acc[1][0]);
            acc[1][1] = fmaf(zi.y, zj.y, acc[1][1]);
            acc[1][2] = fmaf(zi.y, zj.z, acc[1][2]);
            acc[1][3] = fmaf(zi.y, zj.w, acc[1][3]);
        }
        __syncthreads();
    }
    float part = 0.f;
#pragma unroll
    for (int m = 0; m < 2; ++m) {
        int i = i0 + ty * 2 + m;
        float sqi_v = sqi[ty * 2 + m];
        float4 d;
        d.x = fmaxf(sqi_v + sqj[tx * 4 + 0] - 2.f * acc[m][0], 0.f);
        d.y = fmaxf(sqi_v + sqj[tx * 4 + 1] - 2.f * acc[m][1], 0.f);
        d.z = fmaxf(sqi_v + sqj[tx * 4 + 2] - 2.f * acc[m][2], 0.f);
        d.w = fmaxf(sqi_v + sqj[tx * 4 + 3] - 2.f * acc[m][3], 0.f);
        *(float4*)&D2[(size_t)i * NN + j0 + tx * 4] = d;
        part += (d.x + d.y) + (d.z + d.w);
    }
#pragma unroll
    for (int off = 32; off > 0; off >>= 1) part += __shfl_down(part, off);
    if ((tid & 63) == 0) red[tid >> 6] = part;
    __syncthreads();
    if (tid == 0) atomicAdd(sig, red[0] + red[1] + red[2] + red[3]);
}

// ---------------- deg_i = sum_j exp(-D2_ij/sigma); Dh_i = rsqrt(deg_i) ----------------
__global__ void k_deg(const float* __restrict__ D2, const float* __restrict__ sig,
                      float* __restrict__ Dh) {
    __shared__ float red[4];
    int i = blockIdx.x, tid = threadIdx.x;
    float inv = 1.f / (sig[0] * (1.f / 1048576.f) + 1e-12f);
    float4 v = *(const float4*)&D2[(size_t)i * NN + tid * 4];
    float s = __expf(-v.x * inv) + __expf(-v.y * inv) + __expf(-v.z * inv) + __expf(-v.w * inv);
#pragma unroll
    for (int off = 32; off > 0; off >>= 1) s += __shfl_down(s, off);
    if ((tid & 63) == 0) red[tid >> 6] = s;
    __syncthreads();
    if (tid == 0) Dh[i] = rsqrtf(red[0] + red[1] + red[2] + red[3]);
}

// ---------------- Lb_ij = bf16( delta_ij - Dh_i Dh_j exp(-D2_ij/sigma) ) ----------------
__global__ void k_L(const float* __restrict__ D2, const float* __restrict__ sig,
                    const float* __restrict__ Dh, ushort* __restrict__ Lb) {
    int i = blockIdx.x, tid = threadIdx.x;
    int j = tid * 4;
    float inv = 1.f / (sig[0] * (1.f / 1048576.f) + 1e-12f);
    float dhi = Dh[i];
    float4 v = *(const float4*)&D2[(size_t)i * NN + j];
    float4 dj = *(const float4*)&Dh[j];
    float4 o;
    o.x = -dhi * dj.x * __expf(-v.x * inv);
    o.y = -dhi * dj.y * __expf(-v.y * inv);
    o.z = -dhi * dj.z * __expf(-v.z * inv);
    o.w = -dhi * dj.w * __expf(-v.w * inv);
    if (i == j + 0) o.x += 1.f;
    if (i == j + 1) o.y += 1.f;
    if (i == j + 2) o.z += 1.f;
    if (i == j + 3) o.w += 1.f;
    ushort4 ob; ob.x = f2bf(o.x); ob.y = f2bf(o.y); ob.z = f2bf(o.z); ob.w = f2bf(o.w);
    *(ushort4*)&Lb[(size_t)i * NN + j] = ob;
}

// ---------------- MFMA conv1d: C[co,p] = sum_{t,ci} Wt[t][co][ci] * Zct[p+t][ci] ----------------
// grid (16 p, 8 co, 2 z), block 256; block tile 32co x 64p; K = 9*128
__global__ __launch_bounds__(256) void k_conv(const ushort* __restrict__ Zct,
        const ushort* __restrict__ Wt, float* __restrict__ C0, ushort* __restrict__ C1b) {
    const int z = blockIdx.z;
    const int p0 = blockIdx.x * 64, co0 = blockIdx.y * 32;
    __shared__ ushort Xs[72 * 136];
    __shared__ ushort Wl[9 * 32 * 136];
    const int tid = threadIdx.x;
    const ushort* Zz = Zct + z * (1032 * 128);
    const ushort* Wz = Wt + (size_t)z * 9 * NHID * NOPEN;
    for (int idx = tid; idx < 1152; idx += 256) {
        int row = idx >> 4, ch = (idx & 15) * 8;
        *(bfrag*)&Xs[row * 136 + ch] = *(const bfrag*)&Zz[(p0 + row) * 128 + ch];
    }
    for (int idx = tid; idx < 4608; idx += 256) {
        int t = idx >> 9, rem = idx & 511;
        int c = rem >> 4, ch = (rem & 15) * 8;
        *(bfrag*)&Wl[(t * 32 + c) * 136 + ch] = *(const bfrag*)&Wz[(t * NHID + co0 + c) * 128 + ch];
    }
    __syncthreads();
    const int l = tid & 63, wv = tid >> 6;
    const int wm = wv >> 1, wn = wv & 1;
    const int lm = l & 15, lq = l >> 4;
    floatx4 acc[2] = {};
    for (int t = 0; t < 9; ++t) {
        const int wbase = (t * 32 + wm * 16 + lm) * 136 + lq * 8;
        const int xbase = (wn * 32 + lm + t) * 136 + lq * 8;
#pragma unroll
        for (int kc = 0; kc < 4; ++kc) {
            bfrag a = *(const bfrag*)&Wl[wbase + kc * 32];
            bfrag b0 = *(const bfrag*)&Xs[xbase + kc * 32];
            acc[0] = __builtin_amdgcn_mfma_f32_16x16x32_bf16(a, b0, acc[0], 0, 0, 0);
            bfrag b1 = *(const bfrag*)&Xs[xbase + 16 * 136 + kc * 32];
            acc[1] = __builtin_amdgcn_mfma_f32_16x16x32_bf16(a, b1, acc[1], 0, 0, 0);
        }
    }
    const int cog = co0 + wm * 16 + lq * 4;
    const int pg = p0 + wn * 32 + lm;
#pragma unroll
    for (int j = 0; j < 2; ++j)
#pragma unroll
        for (int r = 0; r < 4; ++r) {
            if (z == 0) C0[(cog + r) * NN + pg + j * 16] = acc[j][r];
            else        C1b[(cog + r) * NN + pg + j * 16] = f2bf(acc[j][r]);
        }
}

// ---------------- MFMA GEMM vs symmetric L: split-K 2, 64x64 tiles ----------------
// grid (16 nt, M/64 mt, 2 ksp); P[ksp] = X[:, ksp*512:+512] @ L[.., :]
__global__ __launch_bounds__(256) void k_xl(const ushort* __restrict__ X,
        const ushort* __restrict__ Lb, float* __restrict__ P, int M) {
    __shared__ __align__(16) ushort As[64 * 136];
    __shared__ __align__(16) ushort Bs[64 * 136];
    const int tid = threadIdx.x;
    const int lane = tid & 63, wave = tid >> 6;
    const int wm = wave >> 1, wn = wave & 1;
    const int lm = lane & 15, lq = lane >> 4;
    const int n0 = blockIdx.x * 64, m0 = blockIdx.y * 64, k0 = blockIdx.z * 512;
    float* Out = P + (size_t)blockIdx.z * M * NN;
    floatx4 acc[2][2] = {};
    for (int kc = k0; kc < k0 + 512; kc += 128) {
#pragma unroll
        for (int r = 0; r < 4; ++r) {
            int q = r * 256 + tid;
            int row = q >> 4, ch = (q & 15) * 8;
            *(bfrag*)&As[row * 136 + ch] = *(const bfrag*)&X[(m0 + row) * NN + kc + ch];
            *(bfrag*)&Bs[row * 136 + ch] = *(const bfrag*)&Lb[(n0 + row) * NN + kc + ch];
        }
        __syncthreads();
#pragma unroll
        for (int ks = 0; ks < 4; ++ks) {
            bfrag a[2], b[2];
#pragma unroll
            for (int i = 0; i < 2; ++i)
                a[i] = *(const bfrag*)&As[(wm * 32 + i * 16 + lm) * 136 + ks * 32 + lq * 8];
#pragma unroll
            for (int j = 0; j < 2; ++j)
                b[j] = *(const bfrag*)&Bs[(wn * 32 + j * 16 + lm) * 136 + ks * 32 + lq * 8];
#pragma unroll
            for (int i = 0; i < 2; ++i)
#pragma unroll
                for (int j = 0; j < 2; ++j)
                    acc[i][j] = __builtin_amdgcn_mfma_f32_16x16x32_bf16(a[i], b[j], acc[i][j], 0, 0, 0);
        }
        __syncthreads();
    }
    const int mg0 = m0 + wm * 32 + lq * 4;
    const int ng0 = n0 + wn * 32 + lm;
#pragma unroll
    for (int i = 0; i < 2; ++i)
#pragma unroll
        for (int j = 0; j < 2; ++j)
#pragma unroll
            for (int r = 0; r < 4; ++r)
                Out[(size_t)(mg0 + i * 16 + r) * NN + ng0 + j * 16] = acc[i][j][r];
}

// ---------------- instance norm (redundant per-block stats) + relu + bf16 + transpose ----------------
// grid (16 p, 4 co64, 2 arr); arr1 sums the 2 xl1 split-K partials inline
__global__ __launch_bounds__(256) void k_normT(const float* __restrict__ C0,
        const float* __restrict__ A1, ushort* __restrict__ At0, ushort* __restrict__ At1) {
    const int arr = blockIdx.z;
    const int p0 = blockIdx.x * 64, co0 = blockIdx.y * 64;
    const float* in = arr ? A1 : C0;
    const float* in2 = arr ? A1 + (size_t)NHID * NN : nullptr;
    ushort* out = arr ? At1 : At0;
    __shared__ float ps[256], pqv[256], mu[64], rsx[64];
    __shared__ ushort Ls[64 * 72];
    const int tid = threadIdx.x;
    {
        const int ch = tid >> 2, q = tid & 3;
        const float* row = in + (size_t)(co0 + ch) * NN;
        const float* row2 = in2 ? in2 + (size_t)(co0 + ch) * NN : row;
        float s = 0.f, qq = 0.f;
        for (int j = 0; j < 64; ++j) {
            int f = (j * 4 + q) * 4;
            float4 v = *(const float4*)&row[f];
            if (in2) {
                float4 w = *(const float4*)&row2[f];
                v.x += w.x; v.y += w.y; v.z += w.z; v.w += w.w;
            }
            s += (v.x + v.y) + (v.z + v.w);
            qq += (v.x * v.x + v.y * v.y) + (v.z * v.z + v.w * v.w);
        }
        ps[ch * 4 + q] = s; pqv[ch * 4 + q] = qq;
    }
    __syncthreads();
    if (tid < 64) {
        float S = ps[tid * 4] + ps[tid * 4 + 1] + ps[tid * 4 + 2] + ps[tid * 4 + 3];
        float Q = pqv[tid * 4] + pqv[tid * 4 + 1] + pqv[tid * 4 + 2] + pqv[tid * 4 + 3];
        float mean = S * (1.f / NN);
        float var = Q * (1.f / NN) - mean * mean;
        mu[tid] = mean;
        rsx[tid] = rsqrtf(var + IN_EPS);
    }
    __syncthreads();
#pragma unroll
    for (int r = 0; r < 4; ++r) {
        int idx = r * 256 + tid;
        int col = idx >> 4, pq2 = idx & 15;
        float4 v = *(const float4*)(in + (size_t)(co0 + col) * NN + p0 + pq2 * 4);
        if (in2) {
            float4 w = *(const float4*)(in2 + (size_t)(co0 + col) * NN + p0 + pq2 * 4);
            v.x += w.x; v.y += w.y; v.z += w.z; v.w += w.w;
        }
        float m = mu[col], sc = rsx[col];
        Ls[(pq2 * 4 + 0) * 72 + col] = f2bf(fmaxf((v.x - m) * sc, 0.f));
        Ls[(pq2 * 4 + 1) * 72 + col] = f2bf(fmaxf((v.y - m) * sc, 0.f));
        Ls[(pq2 * 4 + 2) * 72 + col] = f2bf(fmaxf((v.z - m) * sc, 0.f));
        Ls[(pq2 * 4 + 3) * 72 + col] = f2bf(fmaxf((v.w - m) * sc, 0.f));
    }
    __syncthreads();
#pragma unroll
    for (int r = 0; r < 2; ++r) {
        int idx = r * 256 + tid;
        int row = idx >> 3, ch8 = (idx & 7) * 8;
        *(bfrag*)&out[(size_t)(p0 + row + 4) * 256 + co0 + ch8] = *(const bfrag*)&Ls[row * 72 + ch8];
    }
}

// ---------------- MFMA convT: T[ci,p] = sum_{t,co} WtT[t][ci][co] * At[p+8-t][co] ----------------
// grid (16 p, 8 ci16, 2 z), block 256; block tile 16ci x 64p; K = 9*256
__global__ __launch_bounds__(256) void k_convT(const ushort* __restrict__ At0,
        const ushort* __restrict__ At1, const ushort* __restrict__ WtT,
        float* __restrict__ Tacc, ushort* __restrict__ T1b) {
    const int z = blockIdx.z;
    const int p0 = blockIdx.x * 64, ci0 = blockIdx.y * 16;
    __shared__ ushort Al[72 * 264];
    __shared__ ushort Wl[9 * 16 * 264];
    const ushort* A = z ? At1 : At0;
    const ushort* Wz = WtT + (size_t)z * 9 * NOPEN * NHID;
    const int tid = threadIdx.x;
    for (int idx = tid; idx < 2304; idx += 256) {
        int row = idx >> 5, ch = (idx & 31) * 8;
        *(bfrag*)&Al[row * 264 + ch] = *(const bfrag*)&A[(p0 + row) * 256 + ch];
    }
    for (int idx = tid; idx < 4608; idx += 256) {
        int t = idx >> 9, rem = idx & 511;
        int c = rem >> 5, ch = (rem & 31) * 8;
        *(bfrag*)&Wl[(t * 16 + c) * 264 + ch] = *(const bfrag*)&Wz[(t * NOPEN + ci0 + c) * 256 + ch];
    }
    __syncthreads();
    const int l = tid & 63, wv = tid >> 6;
    const int lm = l & 15, lq = l >> 4;
    floatx4 acc0 = {}, acc1 = {};
    for (int t = 0; t < 9; ++t) {
        const int abase = (wv * 16 + lm + 8 - t) * 264 + lq * 8;
        const int wbase = (t * 16 + lm) * 264 + lq * 8;
#pragma unroll
        for (int kc = 0; kc < 8; kc += 2) {
            bfrag a0 = *(const bfrag*)&Wl[wbase + kc * 32];
            bfrag b0 = *(const bfrag*)&Al[abase + kc * 32];
            acc0 = __builtin_amdgcn_mfma_f32_16x16x32_bf16(a0, b0, acc0, 0, 0, 0);
            bfrag a1 = *(const bfrag*)&Wl[wbase + kc * 32 + 32];
            bfrag b1 = *(const bfrag*)&Al[abase + kc * 32 + 32];
            acc1 = __builtin_amdgcn_mfma_f32_16x16x32_bf16(a1, b1, acc1, 0, 0, 0);
        }
    }
    floatx4 acc = acc0 + acc1;
    const int cig = ci0 + lq * 4;
    const int pg = p0 + wv * 16 + lm;
#pragma unroll
    for (int r = 0; r < 4; ++r) {
        if (z == 0) Tacc[(cig + r) * NN + pg] = acc[r];
        else        T1b[(cig + r) * NN + pg] = f2bf(acc[r]);
    }
}

// ---------------- leapfrog + next-layer Zct + next-layer weight prep + sig=0 ----------------
// grid 273: v<128 leap; 128..271 prepw(lnext) if doprep; v=272 zero sig
__global__ __launch_bounds__(256) void k_leap(const float* __restrict__ A2,
        const float* __restrict__ Tacc, const float* __restrict__ Zc, float* __restrict__ Zo,
        const float* __restrict__ BiasN, ushort* __restrict__ Zct,
        const float* __restrict__ W, ushort* __restrict__ Wt, ushort* __restrict__ WtT,
        float* __restrict__ sig, int lnext, int doprep) {
    const int v = blockIdx.x, tid = threadIdx.x;
    if (v < 128) {
        int off = (v * 256 + tid) * 4;
        float4 a = *(const float4*)&Tacc[off];
        float4 q0 = *(const float4*)&A2[off];
        float4 q1 = *(const float4*)&A2[NOPEN * NN + off];
        a.x += q0.x + q1.x; a.y += q0.y + q1.y; a.z += q0.z + q1.z; a.w += q0.w + q1.w;
        float4 zc = *(const float4*)&Zc[off];
        float4 zo = *(const float4*)&Zo[off];
        float4 zn;
        zn.x = 2.f * zc.x - zo.x - H2 * a.x;
        zn.y = 2.f * zc.y - zo.y - H2 * a.y;
        zn.z = 2.f * zc.z - zo.z - H2 * a.z;
        zn.w = 2.f * zc.w - zo.w - H2 * a.w;
        *(float4*)&Zo[off] = zn;
        int ci = off >> 10, n = off & 1023;
#pragma unroll
        for (int z = 0; z < 2; ++z) {
            float bz = BiasN[z * NOPEN + ci];
            ushort* Zz = Zct + z * (1032 * 128);
            Zz[(n + 4) * 128 + ci] = f2bf(zn.x + bz);
            Zz[(n + 5) * 128 + ci] = f2bf(zn.y + bz);
            Zz[(n + 6) * 128 + ci] = f2bf(zn.z + bz);
            Zz[(n + 7) * 128 + ci] = f2bf(zn.w + bz);
        }
    } else if (v < 272) {
        if (doprep) prepw_piece(W, Wt, WtT, v - 128, lnext, tid);
    } else {
        if (tid == 0) sig[0] = 0.f;
    }
}

// ---------------- closing: out = concat(Kclose @ Zc, Kclose @ Zold) ----------------
__global__ void k_close(const float* __restrict__ Kclose, const float* __restrict__ Zc,
                        const float* __restrict__ Zold, float* __restrict__ out) {
    int n = blockIdx.x * 256 + threadIdx.x;
    int o = blockIdx.y;
    const float* Zb = blockIdx.z ? Zold : Zc;
    float a = 0.f;
#pragma unroll
    for (int c = 0; c < NOPEN; ++c) a = fmaf(Kclose[o * NOPEN + c], Zb[c * NN + n], a);
    out[blockIdx.z * (NCLOSE * NN) + o * NN + n] = a;
}

extern "C" void kernel_launch(void* const* d_in, const int* in_sizes, int n_in,
                              void* d_out, int out_size, void* d_ws, size_t ws_size,
                              hipStream_t stream) {
    const float* Z      = (const float*)d_in[0];
    const float* Kopen  = (const float*)d_in[1];
    const float* Kclose = (const float*)d_in[2];
    const float* W      = (const float*)d_in[3];
    const float* Bias   = (const float*)d_in[4];
    float* out = (float*)d_out;
    float* ws  = (float*)d_ws;

    // workspace layout (float units)
    float* Zb0  = ws + 0;         // 131072
    float* Zb1  = ws + 131072;    // 131072
    float* D2   = ws + 262144;    // 1048576
    float* C0   = ws + 1310720;   // 262144
    float* A1   = ws + 1572864;   // 524288 (2 splits)
    float* A2   = ws + 2097152;   // 262144 (2 splits)
    float* Tacc = ws + 2359296;   // 131072
    float* Dh   = ws + 2490368;   // 1024
    float* sig  = ws + 2491392;   // 1024
    ushort* Lb  = (ushort*)(ws + 2492416); // 1024*1024 us
    ushort* C1b = (ushort*)(ws + 3016704); // 256*1024 us
    ushort* T1b = (ushort*)(ws + 3147776); // 128*1024 us
    ushort* Zct = (ushort*)(ws + 3213312); // 2*1032*128 us
    ushort* At0 = (ushort*)(ws + 3345408); // 1032*256 us
    ushort* At1 = (ushort*)(ws + 3477504); // 1032*256 us
    ushort* Wt  = (ushort*)(ws + 3609600); // 2*9*256*128 us
    ushort* WtT = (ushort*)(ws + 3904512); // 2*9*128*256 us  (end 4199424 floats = 16.8 MB)

    k_open<<<dim3(657), 256, 0, stream>>>(Kopen, Z, Zb0, Zb1, Bias, Zct, At0, At1,
                                          W, Wt, WtT, sig);

    float* Zc = Zb0;
    float* Zold = Zb1;
    for (int i = 0; i < NLAYERS; ++i) {
        if (i % 10 == 0) {
            k_d2<<<dim3(16, 32), 256, 0, stream>>>(Zc, D2, sig);
            k_deg<<<dim3(NN), 256, 0, stream>>>(D2, sig, Dh);
            k_L<<<dim3(NN), 256, 0, stream>>>(D2, sig, Dh, Lb);
        }
        k_conv<<<dim3(16, 8, 2), 256, 0, stream>>>(Zct, Wt, C0, C1b);
        k_xl<<<dim3(16, 4, 2), 256, 0, stream>>>(C1b, Lb, A1, NHID);
        k_normT<<<dim3(16, 4, 2), 256, 0, stream>>>(C0, A1, At0, At1);
        k_convT<<<dim3(16, 8, 2), 256, 0, stream>>>(At0, At1, WtT, Tacc, T1b);
        k_xl<<<dim3(16, 2, 2), 256, 0, stream>>>(T1b, Lb, A2, NOPEN);
        int lnext = (i + 1 < NLAYERS) ? i + 1 : NLAYERS - 1;
        k_leap<<<dim3(273), 256, 0, stream>>>(A2, Tacc, Zc, Zold,
                                              Bias + (size_t)lnext * 2 * NOPEN, Zct,
                                              W, Wt, WtT, sig, lnext, (i + 1 < NLAYERS) ? 1 : 0);
        float* tmp = Zc; Zc = Zold; Zold = tmp;
    }

    k_close<<<dim3(4, NCLOSE, 2), 256, 0, stream>>>(Kclose, Zc, Zold, out);
}

// Round 6
// 2122.297 us; speedup vs baseline: 4.7841x; 1.2652x over previous
//
#include <hip/hip_runtime.h>

#define NN 1024
#define NOPEN 128
#define NHID 256
#define NSTART 40
#define NCLOSE 3
#define NLAYERS 40
#define KSZ 9

static constexpr float H2 = 0.01f;     // h*h, h = 0.1
static constexpr float IN_EPS = 1e-5f; // instance norm eps

using floatx4 = __attribute__((ext_vector_type(4))) float;
using bfrag = __attribute__((ext_vector_type(8))) short; // 8 bf16 = 4 VGPRs

__device__ __forceinline__ ushort f2bf(float f) {
    union { float f; unsigned u; } v; v.f = f;
    unsigned r = v.u + 0x7fffu + ((v.u >> 16) & 1u); // RNE
    return (ushort)(r >> 16);
}

// weight transpose prep: lb<72 -> Wt[z][t][co][ci]; else WtT[z][t][ci][co]
__device__ __forceinline__ void prepw_piece(const float* __restrict__ W, ushort* __restrict__ Wt,
                                            ushort* __restrict__ WtT, int lb, int lsrc, int tid) {
    if (lb < 72) {
        int q = lb; int coq = q & 3; q >>= 2; int t = q % 9, z = q / 9;
        const float* Wz = W + (size_t)(lsrc * 2 + z) * (NHID * NOPEN * KSZ);
        ushort* Wo = Wt + ((size_t)z * 9 + t) * (NHID * NOPEN);
#pragma unroll
        for (int r = 0; r < 32; ++r) {
            int idx = r * 256 + tid;
            int co = coq * 64 + (idx >> 7), ci = idx & 127;
            Wo[co * NOPEN + ci] = f2bf(Wz[co * (NOPEN * KSZ) + ci * KSZ + t]);
        }
    } else {
        int q = lb - 72; int ciq = q & 3; q >>= 2; int t = q % 9, z = q / 9;
        const float* Wz = W + (size_t)(lsrc * 2 + z) * (NHID * NOPEN * KSZ);
        ushort* Wo = WtT + ((size_t)z * 9 + t) * (NOPEN * NHID);
#pragma unroll
        for (int r = 0; r < 32; ++r) {
            int idx = r * 256 + tid;
            int ci = ciq * 32 + (idx >> 8), co = idx & 255;
            Wo[ci * NHID + co] = f2bf(Wz[co * (NOPEN * KSZ) + ci * KSZ + t]);
        }
    }
}

// ---------------- opening: Zc/Zold/Zct(layer0) + weight prep(layer0) + pads + sig=0 ----------------
__global__ __launch_bounds__(256) void k_open(const float* __restrict__ Kopen, const float* __restrict__ Z,
                       float* __restrict__ Zc, float* __restrict__ Zold,
                       const float* __restrict__ Bias0, ushort* __restrict__ Zct,
                       ushort* __restrict__ At0, ushort* __restrict__ At1,
                       const float* __restrict__ W, ushort* __restrict__ Wt,
                       ushort* __restrict__ WtT, float* __restrict__ sig) {
    const int v = blockIdx.x, tid = threadIdx.x;
    if (v < 512) {
        int o = v >> 2, n = (v & 3) * 256 + tid;
        float acc = 0.f;
#pragma unroll
        for (int s = 0; s < NSTART; ++s)
            acc = fmaf(Kopen[o * NSTART + s], Z[s * NN + n], acc);
        Zc[o * NN + n] = acc;
        Zold[o * NN + n] = acc;
#pragma unroll
        for (int z = 0; z < 2; ++z)
            Zct[z * (1032 * 128) + (n + 4) * 128 + o] = f2bf(acc + Bias0[z * NOPEN + o]);
    } else if (v < 656) {
        prepw_piece(W, Wt, WtT, v - 512, 0, tid);
    } else {
        if (tid == 0) sig[0] = 0.f;
        for (int idx = tid; idx < 1024; idx += 256) {
            int z = idx >> 9, rr = idx & 511;
            ushort* Zz = Zct + z * (1032 * 128);
            Zz[rr] = 0; Zz[1028 * 128 + rr] = 0;
        }
        for (int idx = tid; idx < 2048; idx += 256) {
            int a = idx >> 10, rr = idx & 1023;
            ushort* A = a ? At1 : At0;
            A[rr] = 0; A[1028 * 256 + rr] = 0;
        }
    }
}

// ---------------- D2 = max(sq_i + sq_j - 2 Z^T Z, 0); sq computed in-block; sum(D2) -> sig ----------------
// grid (16 j-tiles, 32 i-tiles); sig zeroed by previous dispatch
__global__ __launch_bounds__(256) void k_d2(const float* __restrict__ Zc,
                                            float* __restrict__ D2, float* __restrict__ sig) {
    __shared__ __align__(16) float Zi[32 * 36];
    __shared__ __align__(16) float Zj[32 * 68];
    __shared__ float sqi[32], sqj[64];
    __shared__ float red[4];
    const int tid = threadIdx.x;
    const int tx = tid & 15, ty = tid >> 4;
    const int j0 = blockIdx.x * 64, i0 = blockIdx.y * 32;
    if (tid < 32) sqi[tid] = 0.f;
    else if (tid < 96) sqj[tid - 32] = 0.f;
    float acc[2][4] = {};
    for (int c0 = 0; c0 < NOPEN; c0 += 32) {
        for (int idx = tid; idx < 32 * 32; idx += 256) {
            int c = idx >> 5, ii = idx & 31;
            Zi[c * 36 + ii] = Zc[(c0 + c) * NN + i0 + ii];
        }
        for (int idx = tid; idx < 32 * 64; idx += 256) {
            int c = idx >> 6, jj = idx & 63;
            Zj[c * 68 + jj] = Zc[(c0 + c) * NN + j0 + jj];
        }
        __syncthreads();
        if (tid < 32) {
            float s = 0.f;
            for (int c = 0; c < 32; ++c) { float x = Zi[c * 36 + tid]; s = fmaf(x, x, s); }
            sqi[tid] += s;
        } else if (tid < 96) {
            int jj = tid - 32;
            float s = 0.f;
            for (int c = 0; c < 32; ++c) { float x = Zj[c * 68 + jj]; s = fmaf(x, x, s); }
            sqj[jj] += s;
        }
#pragma unroll 8
        for (int c = 0; c < 32; ++c) {
            float2 zi = *(const float2*)&Zi[c * 36 + ty * 2];
            float4 zj = *(const float4*)&Zj[c * 68 + tx * 4];
            acc[0][0] = fmaf(zi.x, zj.x, acc[0][0]);
            acc[0][1] = fmaf(zi.x, zj.y, acc[0][1]);
            acc[0][2] = fmaf(zi.x, zj.z, acc[0][2]);
            acc[0][3] = fmaf(zi.x, zj.w, acc[0][3]);
            acc[1][0] = fmaf(zi.y, zj.x, acc[1][0]);
            acc[1][1] = fmaf(zi.y, zj.y, acc[1][1]);
            acc[1][2] = fmaf(zi.y, zj.z, acc[1][2]);
            acc[1][3] = fmaf(zi.y, zj.w, acc[1][3]);
        }
        __syncthreads();
    }
    float part = 0.f;
#pragma unroll
    for (int m = 0; m < 2; ++m) {
        int i = i0 + ty * 2 + m;
        float sqi_v = sqi[ty * 2 + m];
        float4 d;
        d.x = fmaxf(sqi_v + sqj[tx * 4 + 0] - 2.f * acc[m][0], 0.f);
        d.y = fmaxf(sqi_v + sqj[tx * 4 + 1] - 2.f * acc[m][1], 0.f);
        d.z = fmaxf(sqi_v + sqj[tx * 4 + 2] - 2.f * acc[m][2], 0.f);
        d.w = fmaxf(sqi_v + sqj[tx * 4 + 3] - 2.f * acc[m][3], 0.f);
        *(float4*)&D2[(size_t)i * NN + j0 + tx * 4] = d;
        part += (d.x + d.y) + (d.z + d.w);
    }
#pragma unroll
    for (int off = 32; off > 0; off >>= 1) part += __shfl_down(part, off);
    if ((tid & 63) == 0) red[tid >> 6] = part;
    __syncthreads();
    if (tid == 0) atomicAdd(sig, red[0] + red[1] + red[2] + red[3]);
}

// ---------------- deg_i = sum_j exp(-D2_ij/sigma); Dh_i = rsqrt(deg_i) ----------------
__global__ void k_deg(const float* __restrict__ D2, const float* __restrict__ sig,
                      float* __restrict__ Dh) {
    __shared__ float red[4];
    int i = blockIdx.x, tid = threadIdx.x;
    float inv = 1.f / (sig[0] * (1.f / 1048576.f) + 1e-12f);
    float4 v = *(const float4*)&D2[(size_t)i * NN + tid * 4];
    float s = __expf(-v.x * inv) + __expf(-v.y * inv) + __expf(-v.z * inv) + __expf(-v.w * inv);
#pragma unroll
    for (int off = 32; off > 0; off >>= 1) s += __shfl_down(s, off);
    if ((tid & 63) == 0) red[tid >> 6] = s;
    __syncthreads();
    if (tid == 0) Dh[i] = rsqrtf(red[0] + red[1] + red[2] + red[3]);
}

// ---------------- Lb_ij = bf16( delta_ij - Dh_i Dh_j exp(-D2_ij/sigma) ) ----------------
__global__ void k_L(const float* __restrict__ D2, const float* __restrict__ sig,
                    const float* __restrict__ Dh, ushort* __restrict__ Lb) {
    int i = blockIdx.x, tid = threadIdx.x;
    int j = tid * 4;
    float inv = 1.f / (sig[0] * (1.f / 1048576.f) + 1e-12f);
    float dhi = Dh[i];
    float4 v = *(const float4*)&D2[(size_t)i * NN + j];
    float4 dj = *(const float4*)&Dh[j];
    float4 o;
    o.x = -dhi * dj.x * __expf(-v.x * inv);
    o.y = -dhi * dj.y * __expf(-v.y * inv);
    o.z = -dhi * dj.z * __expf(-v.z * inv);
    o.w = -dhi * dj.w * __expf(-v.w * inv);
    if (i == j + 0) o.x += 1.f;
    if (i == j + 1) o.y += 1.f;
    if (i == j + 2) o.z += 1.f;
    if (i == j + 3) o.w += 1.f;
    ushort4 ob; ob.x = f2bf(o.x); ob.y = f2bf(o.y); ob.z = f2bf(o.z); ob.w = f2bf(o.w);
    *(ushort4*)&Lb[(size_t)i * NN + j] = ob;
}

// ---------------- MFMA conv1d: C[co,p] = sum_{t,ci} Wt[t][co][ci] * Zct[p+t][ci] ----------------
// grid (16 p, 8 co, 2 z); block tile 32co x 64p; K = 9*128; single barrier
__global__ __launch_bounds__(256) void k_conv(const ushort* __restrict__ Zct,
        const ushort* __restrict__ Wt, float* __restrict__ C0, ushort* __restrict__ C1b) {
    const int z = blockIdx.z;
    const int p0 = blockIdx.x * 64, co0 = blockIdx.y * 32;
    __shared__ ushort Xs[72 * 136];
    __shared__ ushort Wl[9 * 32 * 136];
    const int tid = threadIdx.x;
    const ushort* Zz = Zct + z * (1032 * 128);
    const ushort* Wz = Wt + (size_t)z * 9 * NHID * NOPEN;
    for (int idx = tid; idx < 1152; idx += 256) {
        int row = idx >> 4, ch = (idx & 15) * 8;
        *(bfrag*)&Xs[row * 136 + ch] = *(const bfrag*)&Zz[(p0 + row) * 128 + ch];
    }
    for (int idx = tid; idx < 4608; idx += 256) {
        int t = idx >> 9, rem = idx & 511;
        int c = rem >> 4, ch = (rem & 15) * 8;
        *(bfrag*)&Wl[(t * 32 + c) * 136 + ch] = *(const bfrag*)&Wz[(t * NHID + co0 + c) * 128 + ch];
    }
    __syncthreads();
    const int l = tid & 63, wv = tid >> 6;
    const int wm = wv >> 1, wn = wv & 1;
    const int lm = l & 15, lq = l >> 4;
    floatx4 acc[2] = {};
    for (int t = 0; t < 9; ++t) {
        const int wbase = (t * 32 + wm * 16 + lm) * 136 + lq * 8;
        const int xbase = (wn * 32 + lm + t) * 136 + lq * 8;
#pragma unroll
        for (int kc = 0; kc < 4; ++kc) {
            bfrag a = *(const bfrag*)&Wl[wbase + kc * 32];
            bfrag b0 = *(const bfrag*)&Xs[xbase + kc * 32];
            acc[0] = __builtin_amdgcn_mfma_f32_16x16x32_bf16(a, b0, acc[0], 0, 0, 0);
            bfrag b1 = *(const bfrag*)&Xs[xbase + 16 * 136 + kc * 32];
            acc[1] = __builtin_amdgcn_mfma_f32_16x16x32_bf16(a, b1, acc[1], 0, 0, 0);
        }
    }
    const int cog = co0 + wm * 16 + lq * 4;
    const int pg = p0 + wn * 32 + lm;
#pragma unroll
    for (int j = 0; j < 2; ++j)
#pragma unroll
        for (int r = 0; r < 4; ++r) {
            if (z == 0) C0[(cog + r) * NN + pg + j * 16] = acc[j][r];
            else        C1b[(cog + r) * NN + pg + j * 16] = f2bf(acc[j][r]);
        }
}

// ---------------- MFMA split-K GEMM: P[s] = X[:, sKc:(s+1)Kc] @ L[sKc:(s+1)Kc, :] ----------------
// round-3 body: single barrier, 64m x 128n block tile, Kc = 128, grid (8 nt, M/64 mt, 8 ksp)
__global__ __launch_bounds__(256) void k_xl_mfma(const ushort* __restrict__ X,
                                                 const ushort* __restrict__ Lb,
                                                 float* __restrict__ P, int M) {
    __shared__ __align__(16) ushort As[64 * 136];
    __shared__ __align__(16) ushort Bs[128 * 136];
    const int tid = threadIdx.x;
    const int lane = tid & 63, wave = tid >> 6;
    const int wm = wave >> 1, wn = wave & 1;
    const int n0 = blockIdx.x * 128, m0 = blockIdx.y * 64, kc = blockIdx.z * 128;
    {
        int q = tid;
#pragma unroll
        for (int r = 0; r < 4; ++r, q += 256) {
            int row = q >> 4, ch = (q & 15) * 8;
            *(bfrag*)&As[row * 136 + ch] = *(const bfrag*)&X[(m0 + row) * NN + kc + ch];
        }
        q = tid;
#pragma unroll
        for (int r = 0; r < 8; ++r, q += 256) {
            int row = q >> 4, ch = (q & 15) * 8;
            *(bfrag*)&Bs[row * 136 + ch] = *(const bfrag*)&Lb[(n0 + row) * NN + kc + ch];
        }
    }
    __syncthreads();
    floatx4 acc[2][4] = {};
    const int lrow = (lane & 15) * 136;
    const int koff = (lane >> 4) * 8;
#pragma unroll
    for (int ks = 0; ks < 4; ++ks) {
        bfrag a[2], b[4];
#pragma unroll
        for (int i = 0; i < 2; ++i)
            a[i] = *(const bfrag*)&As[(wm * 32 + i * 16) * 136 + lrow + ks * 32 + koff];
#pragma unroll
        for (int j = 0; j < 4; ++j)
            b[j] = *(const bfrag*)&Bs[(wn * 64 + j * 16) * 136 + lrow + ks * 32 + koff];
#pragma unroll
        for (int i = 0; i < 2; ++i)
#pragma unroll
            for (int j = 0; j < 4; ++j)
                acc[i][j] = __builtin_amdgcn_mfma_f32_16x16x32_bf16(a[i], b[j], acc[i][j], 0, 0, 0);
    }
    const int mg0 = m0 + wm * 32 + (lane >> 4) * 4;
    const int ng0 = n0 + wn * 64 + (lane & 15);
    const size_t base = (size_t)blockIdx.z * M * NN;
#pragma unroll
    for (int i = 0; i < 2; ++i)
#pragma unroll
        for (int j = 0; j < 4; ++j)
#pragma unroll
            for (int r = 0; r < 4; ++r)
                P[base + (size_t)(mg0 + i * 16 + r) * NN + ng0 + j * 16] = acc[i][j][r];
}

// ---------------- instance norm stats; arr=1 also materializes A1sum = sum_s P1[s] ----------------
// grid (NHID, 2), one channel per block
__global__ void k_inorm(const float* __restrict__ C0, const float* __restrict__ P1,
                        float* __restrict__ A1sum, float* __restrict__ Mu, float* __restrict__ Rs) {
    const int c = blockIdx.x, arr = blockIdx.y, tid = threadIdx.x;
    __shared__ float rs[4], rq[4];
    float4 v;
    if (arr == 0) {
        v = *(const float4*)&C0[c * NN + tid * 4];
    } else {
        v.x = v.y = v.z = v.w = 0.f;
#pragma unroll
        for (int s = 0; s < 8; ++s) {
            float4 p = *(const float4*)&P1[(size_t)(s * NHID + c) * NN + tid * 4];
            v.x += p.x; v.y += p.y; v.z += p.z; v.w += p.w;
        }
        *(float4*)&A1sum[c * NN + tid * 4] = v;
    }
    float s = (v.x + v.y) + (v.z + v.w);
    float q = (v.x * v.x + v.y * v.y) + (v.z * v.z + v.w * v.w);
#pragma unroll
    for (int off = 32; off > 0; off >>= 1) { s += __shfl_down(s, off); q += __shfl_down(q, off); }
    if ((tid & 63) == 0) { rs[tid >> 6] = s; rq[tid >> 6] = q; }
    __syncthreads();
    if (tid == 0) {
        float S = rs[0] + rs[1] + rs[2] + rs[3];
        float Q = rq[0] + rq[1] + rq[2] + rq[3];
        float mean = S * (1.f / NN);
        float var = Q * (1.f / NN) - mean * mean;
        Mu[arr * NHID + c] = mean;
        Rs[arr * NHID + c] = rsqrtf(var + IN_EPS);
    }
}

// ---------------- normalize + relu + bf16 + transpose -> At[pos+4][co] ----------------
// grid (16 p, 4 co64, 2 arr)
__global__ __launch_bounds__(256) void k_normT(const float* __restrict__ C0,
        const float* __restrict__ A1sum, const float* __restrict__ Mu, const float* __restrict__ Rs,
        ushort* __restrict__ At0, ushort* __restrict__ At1) {
    const int arr = blockIdx.z;
    const int p0 = blockIdx.x * 64, co0 = blockIdx.y * 64;
    const float* in = arr ? A1sum : C0;
    ushort* out = arr ? At1 : At0;
    __shared__ ushort Ls[64 * 72];
    const int tid = threadIdx.x;
#pragma unroll
    for (int r = 0; r < 4; ++r) {
        int idx = r * 256 + tid;      // 64 co x 16 p-chunks(4)
        int col = idx >> 4, pq = idx & 15;
        int co = co0 + col;
        float4 v = *(const float4*)&in[(size_t)co * NN + p0 + pq * 4];
        float m = Mu[arr * NHID + co], sc = Rs[arr * NHID + co];
        Ls[(pq * 4 + 0) * 72 + col] = f2bf(fmaxf((v.x - m) * sc, 0.f));
        Ls[(pq * 4 + 1) * 72 + col] = f2bf(fmaxf((v.y - m) * sc, 0.f));
        Ls[(pq * 4 + 2) * 72 + col] = f2bf(fmaxf((v.z - m) * sc, 0.f));
        Ls[(pq * 4 + 3) * 72 + col] = f2bf(fmaxf((v.w - m) * sc, 0.f));
    }
    __syncthreads();
#pragma unroll
    for (int r = 0; r < 2; ++r) {
        int idx = r * 256 + tid;      // 64 rows x 8 chunks(8)
        int row = idx >> 3, ch = (idx & 7) * 8;
        *(bfrag*)&out[(size_t)(p0 + row + 4) * 256 + co0 + ch] = *(const bfrag*)&Ls[row * 72 + ch];
    }
}

// ---------------- MFMA convT: T[ci,p] = sum_{t,co} WtT[t][ci][co] * At[p+8-t][co] ----------------
// grid (16 p, 8 ci16, 2 z); block tile 16ci x 64p; K = 9*256; single barrier
__global__ __launch_bounds__(256) void k_convT(const ushort* __restrict__ At0,
        const ushort* __restrict__ At1, const ushort* __restrict__ WtT,
        float* __restrict__ Tacc, ushort* __restrict__ T1b) {
    const int z = blockIdx.z;
    const int p0 = blockIdx.x * 64, ci0 = blockIdx.y * 16;
    __shared__ ushort Al[72 * 264];
    __shared__ ushort Wl[9 * 16 * 264];
    const ushort* A = z ? At1 : At0;
    const ushort* Wz = WtT + (size_t)z * 9 * NOPEN * NHID;
    const int tid = threadIdx.x;
    for (int idx = tid; idx < 2304; idx += 256) {
        int row = idx >> 5, ch = (idx & 31) * 8;
        *(bfrag*)&Al[row * 264 + ch] = *(const bfrag*)&A[(p0 + row) * 256 + ch];
    }
    for (int idx = tid; idx < 4608; idx += 256) {
        int t = idx >> 9, rem = idx & 511;
        int c = rem >> 5, ch = (rem & 31) * 8;
        *(bfrag*)&Wl[(t * 16 + c) * 264 + ch] = *(const bfrag*)&Wz[(t * NOPEN + ci0 + c) * 256 + ch];
    }
    __syncthreads();
    const int l = tid & 63, wv = tid >> 6;
    const int lm = l & 15, lq = l >> 4;
    floatx4 acc0 = {}, acc1 = {};
    for (int t = 0; t < 9; ++t) {
        const int abase = (wv * 16 + lm + 8 - t) * 264 + lq * 8;
        const int wbase = (t * 16 + lm) * 264 + lq * 8;
#pragma unroll
        for (int kc = 0; kc < 8; kc += 2) {
            bfrag a0 = *(const bfrag*)&Wl[wbase + kc * 32];
            bfrag b0 = *(const bfrag*)&Al[abase + kc * 32];
            acc0 = __builtin_amdgcn_mfma_f32_16x16x32_bf16(a0, b0, acc0, 0, 0, 0);
            bfrag a1 = *(const bfrag*)&Wl[wbase + kc * 32 + 32];
            bfrag b1 = *(const bfrag*)&Al[abase + kc * 32 + 32];
            acc1 = __builtin_amdgcn_mfma_f32_16x16x32_bf16(a1, b1, acc1, 0, 0, 0);
        }
    }
    floatx4 acc = acc0 + acc1;
    const int cig = ci0 + lq * 4;
    const int pg = p0 + wv * 16 + lm;
#pragma unroll
    for (int r = 0; r < 4; ++r) {
        if (z == 0) Tacc[(cig + r) * NN + pg] = acc[r];
        else        T1b[(cig + r) * NN + pg] = f2bf(acc[r]);
    }
}

// ---------------- leapfrog (sum 8 P2 partials) + next Zct + next-layer prepw + sig=0 ----------------
// grid 273: v<128 leap; 128..271 prepw(lnext) if doprep; v=272 zero sig
__global__ __launch_bounds__(256) void k_leap(const float* __restrict__ P2,
        const float* __restrict__ Tacc, const float* __restrict__ Zc, float* __restrict__ Zo,
        const float* __restrict__ BiasN, ushort* __restrict__ Zct,
        const float* __restrict__ W, ushort* __restrict__ Wt, ushort* __restrict__ WtT,
        float* __restrict__ sig, int lnext, int doprep) {
    const int v = blockIdx.x, tid = threadIdx.x;
    if (v < 128) {
        int off = (v * 256 + tid) * 4;
        float4 a = *(const float4*)&Tacc[off];
#pragma unroll
        for (int s = 0; s < 8; ++s) {
            float4 p = *(const float4*)&P2[(size_t)(s << 17) + off];
            a.x += p.x; a.y += p.y; a.z += p.z; a.w += p.w;
        }
        float4 zc = *(const float4*)&Zc[off];
        float4 zo = *(const float4*)&Zo[off];
        float4 zn;
        zn.x = 2.f * zc.x - zo.x - H2 * a.x;
        zn.y = 2.f * zc.y - zo.y - H2 * a.y;
        zn.z = 2.f * zc.z - zo.z - H2 * a.z;
        zn.w = 2.f * zc.w - zo.w - H2 * a.w;
        *(float4*)&Zo[off] = zn;
        int ci = off >> 10, n = off & 1023;
#pragma unroll
        for (int z = 0; z < 2; ++z) {
            float bz = BiasN[z * NOPEN + ci];
            ushort* Zz = Zct + z * (1032 * 128);
            Zz[(n + 4) * 128 + ci] = f2bf(zn.x + bz);
            Zz[(n + 5) * 128 + ci] = f2bf(zn.y + bz);
            Zz[(n + 6) * 128 + ci] = f2bf(zn.z + bz);
            Zz[(n + 7) * 128 + ci] = f2bf(zn.w + bz);
        }
    } else if (v < 272) {
        if (doprep) prepw_piece(W, Wt, WtT, v - 128, lnext, tid);
    } else {
        if (tid == 0) sig[0] = 0.f;
    }
}

// ---------------- closing: out = concat(Kclose @ Zc, Kclose @ Zold) ----------------
__global__ void k_close(const float* __restrict__ Kclose, const float* __restrict__ Zc,
                        const float* __restrict__ Zold, float* __restrict__ out) {
    int n = blockIdx.x * 256 + threadIdx.x;
    int o = blockIdx.y;
    const float* Zb = blockIdx.z ? Zold : Zc;
    float a = 0.f;
#pragma unroll
    for (int c = 0; c < NOPEN; ++c) a = fmaf(Kclose[o * NOPEN + c], Zb[c * NN + n], a);
    out[blockIdx.z * (NCLOSE * NN) + o * NN + n] = a;
}

extern "C" void kernel_launch(void* const* d_in, const int* in_sizes, int n_in,
                              void* d_out, int out_size, void* d_ws, size_t ws_size,
                              hipStream_t stream) {
    const float* Z      = (const float*)d_in[0];
    const float* Kopen  = (const float*)d_in[1];
    const float* Kclose = (const float*)d_in[2];
    const float* W      = (const float*)d_in[3];
    const float* Bias   = (const float*)d_in[4];
    float* out = (float*)d_out;
    float* ws  = (float*)d_ws;

    // workspace layout (float units)
    float* Zb0   = ws + 0;         // 131072
    float* Zb1   = ws + 131072;    // 131072
    float* D2    = ws + 262144;    // 1048576
    float* C0    = ws + 1310720;   // 262144
    float* A1sum = ws + 1572864;   // 262144
    float* Tacc  = ws + 1835008;   // 131072
    float* P1    = ws + 1966080;   // 8*256*1024 = 2097152
    float* P2    = ws + 4063232;   // 8*128*1024 = 1048576
    float* Dh    = ws + 5111808;   // 1024
    float* sig   = ws + 5112832;   // 1024
    float* Mu    = ws + 5113856;   // 1024 (512 used)
    float* Rs    = ws + 5114880;   // 1024
    ushort* Lb  = (ushort*)(ws + 5115904); // 1024*1024 us
    ushort* C1b = (ushort*)(ws + 5640192); // 256*1024 us
    ushort* T1b = (ushort*)(ws + 5771264); // 128*1024 us
    ushort* Zct = (ushort*)(ws + 5836800); // 2*1032*128 us
    ushort* At0 = (ushort*)(ws + 5968896); // 1032*256 us
    ushort* At1 = (ushort*)(ws + 6100992); // 1032*256 us
    ushort* Wt  = (ushort*)(ws + 6233088); // 2*9*256*128 us
    ushort* WtT = (ushort*)(ws + 6528000); // 2*9*128*256 us  (end 6822912 floats = 27.3 MB)

    k_open<<<dim3(657), 256, 0, stream>>>(Kopen, Z, Zb0, Zb1, Bias, Zct, At0, At1,
                                          W, Wt, WtT, sig);

    float* Zc = Zb0;
    float* Zold = Zb1;
    for (int i = 0; i < NLAYERS; ++i) {
        if (i % 10 == 0) {
            k_d2<<<dim3(16, 32), 256, 0, stream>>>(Zc, D2, sig);
            k_deg<<<dim3(NN), 256, 0, stream>>>(D2, sig, Dh);
            k_L<<<dim3(NN), 256, 0, stream>>>(D2, sig, Dh, Lb);
        }
        k_conv<<<dim3(16, 8, 2), 256, 0, stream>>>(Zct, Wt, C0, C1b);
        k_xl_mfma<<<dim3(8, 4, 8), 256, 0, stream>>>(C1b, Lb, P1, NHID);   // XL1
        k_inorm<<<dim3(NHID, 2), 256, 0, stream>>>(C0, P1, A1sum, Mu, Rs);
        k_normT<<<dim3(16, 4, 2), 256, 0, stream>>>(C0, A1sum, Mu, Rs, At0, At1);
        k_convT<<<dim3(16, 8, 2), 256, 0, stream>>>(At0, At1, WtT, Tacc, T1b);
        k_xl_mfma<<<dim3(8, 2, 8), 256, 0, stream>>>(T1b, Lb, P2, NOPEN);  // XL2
        int lnext = (i + 1 < NLAYERS) ? i + 1 : NLAYERS - 1;
        k_leap<<<dim3(273), 256, 0, stream>>>(P2, Tacc, Zc, Zold,
                                              Bias + (size_t)lnext * 2 * NOPEN, Zct,
                                              W, Wt, WtT, sig, lnext, (i + 1 < NLAYERS) ? 1 : 0);
        float* tmp = Zc; Zc = Zold; Zold = tmp;
    }

    k_close<<<dim3(4, NCLOSE, 2), 256, 0, stream>>>(Kclose, Zc, Zold, out);
}